// Round 7
// baseline (623.765 us; speedup 1.0000x reference)
//
#include <hip/hip_runtime.h>
#include <stdint.h>
#include <stddef.h>

#define AS1 __attribute__((address_space(1)))
#define AS3 __attribute__((address_space(3)))

typedef __attribute__((ext_vector_type(4))) float f32x4;
typedef __attribute__((ext_vector_type(8))) short bf16x8;

static __device__ __forceinline__ unsigned short f2b(float x) {
  union { float f; uint32_t u; } c; c.f = x;
  return (unsigned short)((c.u + 0x7FFFu + ((c.u >> 16) & 1u)) >> 16);
}
static __device__ __forceinline__ float fsig(float x) {
  return __builtin_amdgcn_rcpf(1.f + __expf(-x));
}
static __device__ __forceinline__ float ftanh(float x) {
  return 1.f - 2.f * __builtin_amdgcn_rcpf(__expf(2.f * x) + 1.f);
}

// ---------------- prep kernels ----------------

__global__ __launch_bounds__(256) void k_cvt_bf16(const float* __restrict__ s,
                                                  unsigned short* __restrict__ d,
                                                  int n4) {
  int i = blockIdx.x * 256 + threadIdx.x;
  int stride = gridDim.x * 256;
  for (; i < n4; i += stride) {
    float4 v = ((const float4*)s)[i];
    ushort4 o;
    o.x = f2b(v.x); o.y = f2b(v.y); o.z = f2b(v.z); o.w = f2b(v.w);
    ((ushort4*)d)[i] = o;
  }
}

// row-permuted f32->bf16: permuted row rp = w*64 + q*16 + j  <-  src row q*512 + w*16 + j
__global__ __launch_bounds__(128) void k_cvt_perm(const float* __restrict__ s,
                                                  unsigned short* __restrict__ d) {
  int rp = blockIdx.x;
  int w = rp >> 6, q = (rp >> 4) & 3, j = rp & 15;
  int rs = q * 512 + w * 16 + j;
  float4 v = ((const float4*)(s + (size_t)rs * 512))[threadIdx.x];
  ushort4 o;
  o.x = f2b(v.x); o.y = f2b(v.y); o.z = f2b(v.z); o.w = f2b(v.w);
  ((ushort4*)(d + (size_t)rp * 512))[threadIdx.x] = o;
}

__global__ __launch_bounds__(256) void k_bias_perm(const float* __restrict__ a,
                                                   const float* __restrict__ b,
                                                   float* __restrict__ o) {
  int rp = blockIdx.x * 256 + threadIdx.x;
  if (rp < 2048) {
    int w = rp >> 6, q = (rp >> 4) & 3, j = rp & 15;
    int rs = q * 512 + w * 16 + j;
    o[rp] = a[rs] + b[rs];
  }
}

// row m = t*16+b  <-  emb[xs[b][t]]  (bf16)
__global__ __launch_bounds__(128) void k_emb_gather(const int* __restrict__ xs,
                                                    const float* __restrict__ emb,
                                                    unsigned short* __restrict__ out) {
  int m = blockIdx.x;
  int tok = xs[(m & 15) * 128 + (m >> 4)];
  float4 v = ((const float4*)(emb + (size_t)tok * 512))[threadIdx.x];
  ushort4 o;
  o.x = f2b(v.x); o.y = f2b(v.y); o.z = f2b(v.z); o.w = f2b(v.w);
  ((ushort4*)(out + (size_t)m * 512))[threadIdx.x] = o;
}

// ---------------- bf16 GEMM, B^T layout (m97-style) ----------------
__global__ __launch_bounds__(256) void k_gemm_bt(const unsigned short* __restrict__ A,
                                                 const unsigned short* __restrict__ Bt,
                                                 const float* __restrict__ bias,
                                                 float* __restrict__ C,
                                                 int M, int N, int K) {
  __shared__ unsigned short As[128 * 32];
  __shared__ unsigned short Bs[128 * 32];
  const int tiles_n = N >> 7;
  const int tm = blockIdx.x / tiles_n;
  const int tn = blockIdx.x % tiles_n;
  const int m0 = tm << 7, n0 = tn << 7;
  const int tid = threadIdx.x;
  const int wave = tid >> 6, lane = tid & 63;
  const int wr = wave >> 1, wc = wave & 1;
  f32x4 acc[4][4] = {};

  const int lo = wave * 2048 + lane * 16;
  for (int k0 = 0; k0 < K; k0 += 32) {
#pragma unroll
    for (int i = 0; i < 2; ++i) {
      int o = lo + i * 1024;
      int row = o >> 6, kb = o & 63;
      __builtin_amdgcn_global_load_lds(
          (const AS1 uint32_t*)((const char*)A + ((size_t)(m0 + row) * K + k0) * 2 + kb),
          (AS3 uint32_t*)((char*)As + wave * 2048 + i * 1024), 16, 0, 0);
    }
#pragma unroll
    for (int i = 0; i < 2; ++i) {
      int o = lo + i * 1024;
      int row = o >> 6, kb = o & 63;
      __builtin_amdgcn_global_load_lds(
          (const AS1 uint32_t*)((const char*)Bt + ((size_t)(n0 + row) * K + k0) * 2 + kb),
          (AS3 uint32_t*)((char*)Bs + wave * 2048 + i * 1024), 16, 0, 0);
    }
    __syncthreads();
    bf16x8 af[4], bfr[4];
    const int lrow = lane & 15;
    const int kb16 = (lane >> 4) * 16;
#pragma unroll
    for (int i = 0; i < 4; ++i)
      af[i] = *(const bf16x8*)((const char*)As + (wr * 64 + i * 16 + lrow) * 64 + kb16);
#pragma unroll
    for (int j = 0; j < 4; ++j)
      bfr[j] = *(const bf16x8*)((const char*)Bs + (wc * 64 + j * 16 + lrow) * 64 + kb16);
#pragma unroll
    for (int i = 0; i < 4; ++i)
#pragma unroll
      for (int j = 0; j < 4; ++j)
        acc[i][j] = __builtin_amdgcn_mfma_f32_16x16x32_bf16(af[i], bfr[j], acc[i][j], 0, 0, 0);
    __syncthreads();
  }
#pragma unroll
  for (int j = 0; j < 4; ++j) {
    int col = n0 + wc * 64 + j * 16 + (lane & 15);
    float bv = bias[col];
#pragma unroll
    for (int i = 0; i < 4; ++i) {
      int r0 = m0 + wr * 64 + i * 16 + (lane >> 4) * 4;
#pragma unroll
      for (int r = 0; r < 4; ++r)
        C[(size_t)(r0 + r) * N + col] = acc[i][j][r] + bv;
    }
  }
}

// ---------------- MFMA LSTM: 32 WGs x 1 wave, agent-scope flag+bulk exchange ----
// Proven-correct primitives (rounds 3/4): __hip_atomic_* RELAXED/AGENT, which
// meet at the IF$ (no L1/L2 staleness possible). New structure splits
// detection from transfer:
//   producer: 4 relaxed-agent h-stores -> s_waitcnt vmcnt(0) (stores are
//             already at the coherence point when retired; no cache
//             maintenance) -> lane0 flag store (relaxed agent).
//   consumer: spin on ONE lane-parallel flag load (32 dwords/sweep, not
//             16KB) -> bulk-load the slot once -> sentinel backstop check.
// gp prefetch issues AFTER the flag store so the producer drain never waits
// on an in-flight HBM load.

__global__ __launch_bounds__(64, 1) void k_lstm(const float* __restrict__ gp,
                                                const unsigned short* __restrict__ wp,
                                                const float* __restrict__ encc,
                                                unsigned short* __restrict__ hsb,
                                                uint32_t* __restrict__ flags) {
  const int w = blockIdx.x;    // worker 0..31
  const int l = threadIdx.x;   // 0..63
  const int lr = l & 15;       // n-col within tile / A batch row
  const int lk = l >> 4;       // k-slice quarter (16B)
  const int col = w * 16 + lr;

  // W_hh fragments, resident in the unified VGPR/AGPR file
  bf16x8 bfr[4][16];
#pragma unroll
  for (int j = 0; j < 4; ++j)
#pragma unroll
    for (int ks = 0; ks < 16; ++ks)
      bfr[j][ks] = *(const bf16x8*)((const char*)wp +
          (size_t)(w * 64 + j * 16 + lr) * 1024 + ks * 64 + lk * 16);

  // c-state: 4 batches (lk*4+r) x col, f32, in-lane
  float cst[4];
#pragma unroll
  for (int r = 0; r < 4; ++r) cst[r] = encc[(lk * 4 + r) * 512 + col];

  const uint64_t K1 = 0x0001000100010001ull;
  const uint64_t K8 = 0x8000800080008000ull;
  const int u64off = lr * 128 + lk * 2;  // lane's base u64 index within a slot

  // pre-gates for step 0 (consumed in the epilogue; double-buffered)
  float gnx[4][4];
#pragma unroll
  for (int j = 0; j < 4; ++j)
#pragma unroll
    for (int r = 0; r < 4; ++r)
      gnx[j][r] = gp[(size_t)(lk * 4 + r) * 2048 + w * 64 + j * 16 + lr];

  for (int t = 0; t < 128; ++t) {
    float gcur[4][4];
#pragma unroll
    for (int j = 0; j < 4; ++j)
#pragma unroll
      for (int r = 0; r < 4; ++r) gcur[j][r] = gnx[j][r];

    // ---- flag poll: one lane-parallel dword load per sweep ----
    if (t) {
      const uint32_t* fp = flags + (size_t)(t - 1) * 32 + (l & 31);
      int guard = 0;
      for (;;) {
        uint32_t fl = __hip_atomic_load(fp, __ATOMIC_RELAXED,
                                        __HIP_MEMORY_SCOPE_AGENT);
        if (__all(fl != 0u)) break;
        __builtin_amdgcn_s_sleep(1);
        if (++guard > (1 << 20)) break;  // tripwire: wrong, not hung
      }
    }

    // ---- bulk-load the slot once (batched, one round trip) ----
    union AF { uint64_t q[2]; bf16x8 v; } af[16];
    const uint64_t* hb = (const uint64_t*)(hsb + (size_t)t * 8192);
    {
      int guard = 0;
      for (;;) {
#pragma unroll
        for (int ks = 0; ks < 16; ++ks) {
          af[ks].q[0] = __hip_atomic_load(hb + u64off + ks * 8, __ATOMIC_RELAXED,
                                          __HIP_MEMORY_SCOPE_AGENT);
          af[ks].q[1] = __hip_atomic_load(hb + u64off + ks * 8 + 1, __ATOMIC_RELAXED,
                                          __HIP_MEMORY_SCOPE_AGENT);
        }
        uint64_t bad = 0;
#pragma unroll
        for (int ks = 0; ks < 16; ++ks) {
          bad |= (~af[ks].q[0] - K1) & af[ks].q[0] & K8;
          bad |= (~af[ks].q[1] - K1) & af[ks].q[1] & K8;
        }
        if (__all(bad == 0)) break;  // backstop; passes first try if flags hold
        __builtin_amdgcn_s_sleep(1);
        if (++guard > (1 << 20)) break;  // tripwire: wrong, not hung
      }
    }

    // ---- gates = h @ W^T (pre-gates added in the epilogue) ----
    f32x4 acc[4] = {};
#pragma unroll
    for (int ks = 0; ks < 16; ++ks) {
#pragma unroll
      for (int j = 0; j < 4; ++j)
        acc[j] = __builtin_amdgcn_mfma_f32_16x16x32_bf16(af[ks].v, bfr[j][ks],
                                                         acc[j], 0, 0, 0);
    }

    // ---- in-lane LSTM cell; pack col pairs -> relaxed agent dword stores ----
    uint32_t pk[4];
#pragma unroll
    for (int r = 0; r < 4; ++r) {
      float iv = fsig(acc[0][r] + gcur[0][r]);
      float fv = fsig(acc[1][r] + gcur[1][r]);
      float gv = ftanh(acc[2][r] + gcur[2][r]);
      float ov = fsig(acc[3][r] + gcur[3][r]);
      cst[r] = fv * cst[r] + iv * gv;
      float hv = ov * ftanh(cst[r]);
      uint32_t mine = f2b(hv);
      uint32_t other = (uint32_t)__shfl_xor((int)mine, 1);
      pk[r] = mine | (other << 16);
    }
    uint32_t* hout = (uint32_t*)(hsb + (size_t)(t + 1) * 8192);
    if ((lr & 1) == 0) {
#pragma unroll
      for (int r = 0; r < 4; ++r)
        __hip_atomic_store(hout + ((lk * 4 + r) * 512 + col) / 2, pk[r],
                           __ATOMIC_RELAXED, __HIP_MEMORY_SCOPE_AGENT);
    }
    // drain: agent-scope stores are at the coherence point once retired
    asm volatile("s_waitcnt vmcnt(0)" ::: "memory");
    if (l == 0)
      __hip_atomic_store(flags + (size_t)t * 32 + w, 1u,
                         __ATOMIC_RELAXED, __HIP_MEMORY_SCOPE_AGENT);

    // prefetch next step's pre-gates AFTER the flag (off the drain path;
    // completes under next step's poll+load+MFMA)
    if (t < 127) {
#pragma unroll
      for (int j = 0; j < 4; ++j)
#pragma unroll
        for (int r = 0; r < 4; ++r)
          gnx[j][r] = gp[(size_t)((t + 1) * 16 + lk * 4 + r) * 2048 +
                         w * 64 + j * 16 + lr];
    }
  }
}

// ---------------- launch ----------------

extern "C" void kernel_launch(void* const* d_in, const int* in_sizes, int n_in,
                              void* d_out, int out_size, void* d_ws, size_t ws_size,
                              hipStream_t stream) {
  (void)in_sizes; (void)n_in; (void)out_size; (void)ws_size;
  const int* xs = (const int*)d_in[0];
  const float* ench = (const float*)d_in[2];
  const float* encc = (const float*)d_in[3];
  const float* emb  = (const float*)d_in[4];
  const float* Wih  = (const float*)d_in[5];
  const float* Whh  = (const float*)d_in[6];
  const float* bih  = (const float*)d_in[7];
  const float* bhh  = (const float*)d_in[8];
  const float* Wout = (const float*)d_in[9];
  const float* bout = (const float*)d_in[10];
  float* out = (float*)d_out;

  char* ws = (char*)d_ws;
  size_t off = 0;
  auto take = [&](size_t bytes) {
    char* p = ws + off;
    off += (bytes + 255) & ~(size_t)255;
    return p;
  };
  float* gates_pre      = (float*)take(2048ull * 2048 * 4);        // [T*B][4H] permuted cols
  unsigned short* hsb   = (unsigned short*)take(129ull * 16 * 512 * 2);  // h states bf16
  unsigned short* aemb  = (unsigned short*)take(2048ull * 512 * 2);
  unsigned short* wih_b = (unsigned short*)take(2048ull * 512 * 2);      // permuted rows
  unsigned short* wp_b  = (unsigned short*)take(2048ull * 512 * 2);      // permuted W_hh
  unsigned short* wout_b= (unsigned short*)take(32000ull * 512 * 2);
  float* bias1          = (float*)take(2048 * 4);                        // permuted
  uint32_t* flags       = (uint32_t*)take(128ull * 32 * 4);              // step flags

  k_cvt_perm<<<2048, 128, 0, stream>>>(Wih, wih_b);
  k_cvt_perm<<<2048, 128, 0, stream>>>(Whh, wp_b);
  k_cvt_bf16<<<2048, 256, 0, stream>>>(Wout, wout_b, 32000 * 512 / 4);
  k_emb_gather<<<2048, 128, 0, stream>>>(xs, emb, aemb);
  k_bias_perm<<<8, 256, 0, stream>>>(bih, bhh, bias1);

  // slot 0 = enc_h (bf16); slots 1..128 = 0xFFFF sentinel (backstop)
  k_cvt_bf16<<<2, 256, 0, stream>>>(ench, hsb, 16 * 512 / 4);
  hipMemsetAsync(hsb + 16 * 512, 0xFF, 128ull * 16 * 512 * 2, stream);

  // gates_pre = aemb @ W_ih_perm^T + (b_ih + b_hh)_perm
  k_gemm_bt<<<256, 256, 0, stream>>>(aemb, wih_b, bias1, gates_pre, 2048, 2048, 512);

  hipMemsetAsync(flags, 0, 128ull * 32 * 4, stream);
  k_lstm<<<32, 64, 0, stream>>>(gates_pre, wp_b, encc, hsb, flags);

  // logits = hs @ W_out^T + b_out   (A = slots 1..128)
  k_gemm_bt<<<4000, 256, 0, stream>>>(hsb + 16 * 512, wout_b, bout, out, 2048, 32000, 512);
}

// Round 8
// 613.105 us; speedup vs baseline: 1.0174x; 1.0174x over previous
//
#include <hip/hip_runtime.h>
#include <stdint.h>
#include <stddef.h>

#define AS1 __attribute__((address_space(1)))
#define AS3 __attribute__((address_space(3)))

typedef __attribute__((ext_vector_type(4))) float f32x4;
typedef __attribute__((ext_vector_type(8))) short bf16x8;

static __device__ __forceinline__ unsigned short f2b(float x) {
  union { float f; uint32_t u; } c; c.f = x;
  return (unsigned short)((c.u + 0x7FFFu + ((c.u >> 16) & 1u)) >> 16);
}
static __device__ __forceinline__ float fsig(float x) {
  return __builtin_amdgcn_rcpf(1.f + __expf(-x));
}
static __device__ __forceinline__ float ftanh(float x) {
  return 1.f - 2.f * __builtin_amdgcn_rcpf(__expf(2.f * x) + 1.f);
}

// ---------------- prep kernels ----------------

__global__ __launch_bounds__(256) void k_cvt_bf16(const float* __restrict__ s,
                                                  unsigned short* __restrict__ d,
                                                  int n4) {
  int i = blockIdx.x * 256 + threadIdx.x;
  int stride = gridDim.x * 256;
  for (; i < n4; i += stride) {
    float4 v = ((const float4*)s)[i];
    ushort4 o;
    o.x = f2b(v.x); o.y = f2b(v.y); o.z = f2b(v.z); o.w = f2b(v.w);
    ((ushort4*)d)[i] = o;
  }
}

// row-permuted f32->bf16: permuted row rp = w*64 + q*16 + j  <-  src row q*512 + w*16 + j
__global__ __launch_bounds__(128) void k_cvt_perm(const float* __restrict__ s,
                                                  unsigned short* __restrict__ d) {
  int rp = blockIdx.x;
  int w = rp >> 6, q = (rp >> 4) & 3, j = rp & 15;
  int rs = q * 512 + w * 16 + j;
  float4 v = ((const float4*)(s + (size_t)rs * 512))[threadIdx.x];
  ushort4 o;
  o.x = f2b(v.x); o.y = f2b(v.y); o.z = f2b(v.z); o.w = f2b(v.w);
  ((ushort4*)(d + (size_t)rp * 512))[threadIdx.x] = o;
}

__global__ __launch_bounds__(256) void k_bias_perm(const float* __restrict__ a,
                                                   const float* __restrict__ b,
                                                   float* __restrict__ o) {
  int rp = blockIdx.x * 256 + threadIdx.x;
  if (rp < 2048) {
    int w = rp >> 6, q = (rp >> 4) & 3, j = rp & 15;
    int rs = q * 512 + w * 16 + j;
    o[rp] = a[rs] + b[rs];
  }
}

// row m = t*16+b  <-  emb[xs[b][t]]  (bf16)
__global__ __launch_bounds__(128) void k_emb_gather(const int* __restrict__ xs,
                                                    const float* __restrict__ emb,
                                                    unsigned short* __restrict__ out) {
  int m = blockIdx.x;
  int tok = xs[(m & 15) * 128 + (m >> 4)];
  float4 v = ((const float4*)(emb + (size_t)tok * 512))[threadIdx.x];
  ushort4 o;
  o.x = f2b(v.x); o.y = f2b(v.y); o.z = f2b(v.z); o.w = f2b(v.w);
  ((ushort4*)(out + (size_t)m * 512))[threadIdx.x] = o;
}

// ---------------- bf16 GEMM, B^T layout (m97-style) ----------------
__global__ __launch_bounds__(256) void k_gemm_bt(const unsigned short* __restrict__ A,
                                                 const unsigned short* __restrict__ Bt,
                                                 const float* __restrict__ bias,
                                                 float* __restrict__ C,
                                                 int M, int N, int K) {
  __shared__ unsigned short As[128 * 32];
  __shared__ unsigned short Bs[128 * 32];
  const int tiles_n = N >> 7;
  const int tm = blockIdx.x / tiles_n;
  const int tn = blockIdx.x % tiles_n;
  const int m0 = tm << 7, n0 = tn << 7;
  const int tid = threadIdx.x;
  const int wave = tid >> 6, lane = tid & 63;
  const int wr = wave >> 1, wc = wave & 1;
  f32x4 acc[4][4] = {};

  const int lo = wave * 2048 + lane * 16;
  for (int k0 = 0; k0 < K; k0 += 32) {
#pragma unroll
    for (int i = 0; i < 2; ++i) {
      int o = lo + i * 1024;
      int row = o >> 6, kb = o & 63;
      __builtin_amdgcn_global_load_lds(
          (const AS1 uint32_t*)((const char*)A + ((size_t)(m0 + row) * K + k0) * 2 + kb),
          (AS3 uint32_t*)((char*)As + wave * 2048 + i * 1024), 16, 0, 0);
    }
#pragma unroll
    for (int i = 0; i < 2; ++i) {
      int o = lo + i * 1024;
      int row = o >> 6, kb = o & 63;
      __builtin_amdgcn_global_load_lds(
          (const AS1 uint32_t*)((const char*)Bt + ((size_t)(n0 + row) * K + k0) * 2 + kb),
          (AS3 uint32_t*)((char*)Bs + wave * 2048 + i * 1024), 16, 0, 0);
    }
    __syncthreads();
    bf16x8 af[4], bfr[4];
    const int lrow = lane & 15;
    const int kb16 = (lane >> 4) * 16;
#pragma unroll
    for (int i = 0; i < 4; ++i)
      af[i] = *(const bf16x8*)((const char*)As + (wr * 64 + i * 16 + lrow) * 64 + kb16);
#pragma unroll
    for (int j = 0; j < 4; ++j)
      bfr[j] = *(const bf16x8*)((const char*)Bs + (wc * 64 + j * 16 + lrow) * 64 + kb16);
#pragma unroll
    for (int i = 0; i < 4; ++i)
#pragma unroll
      for (int j = 0; j < 4; ++j)
        acc[i][j] = __builtin_amdgcn_mfma_f32_16x16x32_bf16(af[i], bfr[j], acc[i][j], 0, 0, 0);
    __syncthreads();
  }
#pragma unroll
  for (int j = 0; j < 4; ++j) {
    int col = n0 + wc * 64 + j * 16 + (lane & 15);
    float bv = bias[col];
#pragma unroll
    for (int i = 0; i < 4; ++i) {
      int r0 = m0 + wr * 64 + i * 16 + (lane >> 4) * 4;
#pragma unroll
      for (int r = 0; r < 4; ++r)
        C[(size_t)(r0 + r) * N + col] = acc[i][j][r] + bv;
    }
  }
}

// ---------------- MFMA LSTM: 32 WGs x 1 wave, flagless sentinel exchange ----
// hsb: [129][16][512] bf16. Slot 0 = enc_h; step t reads slot t, writes t+1.
// Slots 1..128 pre-filled 0xFFFF (bf16 NaN; h=o*tanh(c) finite -> unreachable).
// ONE serialized IF$ round trip per step: producer issues 4 relaxed-agent
// dword stores (no drain, no flag — every dword self-validates, so store
// order is irrelevant); consumer bulk-loads the 32 u64 fragments (relaxed
// agent, one batched round trip), SWAR-validates (~150 cyc), retries until
// clean. gp prefetch sits in the epilogue: its HBM latency pads only the
// first sweep, which waits ~3000 cyc for the other producers anyway.

__global__ __launch_bounds__(64, 1) void k_lstm(const float* __restrict__ gp,
                                                const unsigned short* __restrict__ wp,
                                                const float* __restrict__ encc,
                                                unsigned short* __restrict__ hsb) {
  const int w = blockIdx.x;    // worker 0..31
  const int l = threadIdx.x;   // 0..63
  const int lr = l & 15;       // n-col within tile / A batch row
  const int lk = l >> 4;       // k-slice quarter (16B)
  const int col = w * 16 + lr;

  // W_hh fragments, resident in the unified VGPR/AGPR file
  bf16x8 bfr[4][16];
#pragma unroll
  for (int j = 0; j < 4; ++j)
#pragma unroll
    for (int ks = 0; ks < 16; ++ks)
      bfr[j][ks] = *(const bf16x8*)((const char*)wp +
          (size_t)(w * 64 + j * 16 + lr) * 1024 + ks * 64 + lk * 16);

  // c-state: 4 batches (lk*4+r) x col, f32, in-lane
  float cst[4];
#pragma unroll
  for (int r = 0; r < 4; ++r) cst[r] = encc[(lk * 4 + r) * 512 + col];

  const uint64_t K1 = 0x0001000100010001ull;
  const uint64_t K8 = 0x8000800080008000ull;
  const int u64off = lr * 128 + lk * 2;  // lane's base u64 index within a slot

  // pre-gates for step 0 (consumed in the epilogue; double-buffered)
  float gnx[4][4];
#pragma unroll
  for (int j = 0; j < 4; ++j)
#pragma unroll
    for (int r = 0; r < 4; ++r)
      gnx[j][r] = gp[(size_t)(lk * 4 + r) * 2048 + w * 64 + j * 16 + lr];

  for (int t = 0; t < 128; ++t) {
    float gcur[4][4];
#pragma unroll
    for (int j = 0; j < 4; ++j)
#pragma unroll
      for (int r = 0; r < 4; ++r) gcur[j][r] = gnx[j][r];

    // ---- single-phase wait: bulk load + SWAR sentinel validate + retry ----
    union AF { uint64_t q[2]; bf16x8 v; } af[16];
    const uint64_t* hb = (const uint64_t*)(hsb + (size_t)t * 8192);
    {
      int guard = 0;
      for (;;) {
#pragma unroll
        for (int ks = 0; ks < 16; ++ks) {
          af[ks].q[0] = __hip_atomic_load(hb + u64off + ks * 8, __ATOMIC_RELAXED,
                                          __HIP_MEMORY_SCOPE_AGENT);
          af[ks].q[1] = __hip_atomic_load(hb + u64off + ks * 8 + 1, __ATOMIC_RELAXED,
                                          __HIP_MEMORY_SCOPE_AGENT);
        }
        uint64_t bad = 0;
#pragma unroll
        for (int ks = 0; ks < 16; ++ks) {
          bad |= (~af[ks].q[0] - K1) & af[ks].q[0] & K8;
          bad |= (~af[ks].q[1] - K1) & af[ks].q[1] & K8;
        }
        if (__all(bad == 0)) break;
        __builtin_amdgcn_s_sleep(1);
        if (++guard > (1 << 20)) break;  // tripwire: wrong, not hung
      }
    }

    // ---- gates = h @ W^T (pre-gates added in the epilogue) ----
    f32x4 acc[4] = {};
#pragma unroll
    for (int ks = 0; ks < 16; ++ks) {
#pragma unroll
      for (int j = 0; j < 4; ++j)
        acc[j] = __builtin_amdgcn_mfma_f32_16x16x32_bf16(af[ks].v, bfr[j][ks],
                                                         acc[j], 0, 0, 0);
    }

    // ---- in-lane LSTM cell; pack col pairs -> relaxed agent dword stores ----
    uint32_t pk[4];
#pragma unroll
    for (int r = 0; r < 4; ++r) {
      float iv = fsig(acc[0][r] + gcur[0][r]);
      float fv = fsig(acc[1][r] + gcur[1][r]);
      float gv = ftanh(acc[2][r] + gcur[2][r]);
      float ov = fsig(acc[3][r] + gcur[3][r]);
      cst[r] = fv * cst[r] + iv * gv;
      float hv = ov * ftanh(cst[r]);
      uint32_t mine = f2b(hv);
      uint32_t other = (uint32_t)__shfl_xor((int)mine, 1);
      pk[r] = mine | (other << 16);
    }
    uint32_t* hout = (uint32_t*)(hsb + (size_t)(t + 1) * 8192);
    if ((lr & 1) == 0) {
#pragma unroll
      for (int r = 0; r < 4; ++r)
        __hip_atomic_store(hout + ((lk * 4 + r) * 512 + col) / 2, pk[r],
                           __ATOMIC_RELAXED, __HIP_MEMORY_SCOPE_AGENT);
    }

    // prefetch next step's pre-gates (issued after the h stores; completes
    // under the next step's multi-thousand-cycle producer wait)
    if (t < 127) {
#pragma unroll
      for (int j = 0; j < 4; ++j)
#pragma unroll
        for (int r = 0; r < 4; ++r)
          gnx[j][r] = gp[(size_t)((t + 1) * 16 + lk * 4 + r) * 2048 +
                         w * 64 + j * 16 + lr];
    }
  }
}

// ---------------- launch ----------------

extern "C" void kernel_launch(void* const* d_in, const int* in_sizes, int n_in,
                              void* d_out, int out_size, void* d_ws, size_t ws_size,
                              hipStream_t stream) {
  (void)in_sizes; (void)n_in; (void)out_size; (void)ws_size;
  const int* xs = (const int*)d_in[0];
  const float* ench = (const float*)d_in[2];
  const float* encc = (const float*)d_in[3];
  const float* emb  = (const float*)d_in[4];
  const float* Wih  = (const float*)d_in[5];
  const float* Whh  = (const float*)d_in[6];
  const float* bih  = (const float*)d_in[7];
  const float* bhh  = (const float*)d_in[8];
  const float* Wout = (const float*)d_in[9];
  const float* bout = (const float*)d_in[10];
  float* out = (float*)d_out;

  char* ws = (char*)d_ws;
  size_t off = 0;
  auto take = [&](size_t bytes) {
    char* p = ws + off;
    off += (bytes + 255) & ~(size_t)255;
    return p;
  };
  float* gates_pre      = (float*)take(2048ull * 2048 * 4);        // [T*B][4H] permuted cols
  unsigned short* hsb   = (unsigned short*)take(129ull * 16 * 512 * 2);  // h states bf16
  unsigned short* aemb  = (unsigned short*)take(2048ull * 512 * 2);
  unsigned short* wih_b = (unsigned short*)take(2048ull * 512 * 2);      // permuted rows
  unsigned short* wp_b  = (unsigned short*)take(2048ull * 512 * 2);      // permuted W_hh
  unsigned short* wout_b= (unsigned short*)take(32000ull * 512 * 2);
  float* bias1          = (float*)take(2048 * 4);                        // permuted

  k_cvt_perm<<<2048, 128, 0, stream>>>(Wih, wih_b);
  k_cvt_perm<<<2048, 128, 0, stream>>>(Whh, wp_b);
  k_cvt_bf16<<<2048, 256, 0, stream>>>(Wout, wout_b, 32000 * 512 / 4);
  k_emb_gather<<<2048, 128, 0, stream>>>(xs, emb, aemb);
  k_bias_perm<<<8, 256, 0, stream>>>(bih, bhh, bias1);

  // slot 0 = enc_h (bf16); slots 1..128 = 0xFFFF sentinel
  k_cvt_bf16<<<2, 256, 0, stream>>>(ench, hsb, 16 * 512 / 4);
  hipMemsetAsync(hsb + 16 * 512, 0xFF, 128ull * 16 * 512 * 2, stream);

  // gates_pre = aemb @ W_ih_perm^T + (b_ih + b_hh)_perm
  k_gemm_bt<<<256, 256, 0, stream>>>(aemb, wih_b, bias1, gates_pre, 2048, 2048, 512);

  k_lstm<<<32, 64, 0, stream>>>(gates_pre, wp_b, encc, hsb);

  // logits = hs @ W_out^T + b_out   (A = slots 1..128)
  k_gemm_bt<<<4000, 256, 0, stream>>>(hsb + 16 * 512, wout_b, bout, out, 2048, 32000, 512);
}